// Round 3
// baseline (382.870 us; speedup 1.0000x reference)
//
#include <hip/hip_runtime.h>
#include <hip/hip_bf16.h>
#include <stdint.h>

typedef __attribute__((ext_vector_type(8))) short bf16x8;
typedef __attribute__((ext_vector_type(4))) float f32x4;
typedef __attribute__((ext_vector_type(4))) unsigned short u16x4;

#define T_SEQ 2048
#define HID_D 2880
#define NH 64
#define NKV 8
#define HD 64
#define QKV_N 5120   // (64+16)*64
#define ATT_N 4096   // 64*64
#define WIN 128
#define RSCALE 0.125f          // D^-0.5
#define MSCALE 1.3465735903f   // 0.1*ln(32)+1

__device__ __forceinline__ unsigned short f2bf(float f) {
  union { float f; unsigned u; } v; v.f = f;
  unsigned r = v.u + 0x7fffu + ((v.u >> 16) & 1u);
  return (unsigned short)(r >> 16);
}

__device__ __forceinline__ void gload_lds16(const void* g, void* l) {
  __builtin_amdgcn_global_load_lds((const __attribute__((address_space(1))) char*)g,
                                   (__attribute__((address_space(3))) char*)l, 16, 0, 0);
}

// ---------------- RMSNorm -> bf16 ----------------
__global__ __launch_bounds__(256) void rmsnorm_kernel(const float* __restrict__ x,
                                                      const float* __restrict__ w,
                                                      unsigned short* __restrict__ t_bf) {
  int row = blockIdx.x;
  const float4* xr4 = (const float4*)(x + (size_t)row * HID_D);
  const float4* w4 = (const float4*)w;
  float ss = 0.f;
  for (int i = threadIdx.x; i < HID_D / 4; i += 256) {
    float4 v = xr4[i];
    ss += v.x * v.x + v.y * v.y + v.z * v.z + v.w * v.w;
  }
  __shared__ float red[256];
  red[threadIdx.x] = ss;
  __syncthreads();
  for (int s = 128; s > 0; s >>= 1) {
    if (threadIdx.x < s) red[threadIdx.x] += red[threadIdx.x + s];
    __syncthreads();
  }
  float rs = rsqrtf(red[0] / (float)HID_D + 1e-5f);
  u16x4* ob = (u16x4*)(t_bf + (size_t)row * HID_D);
  for (int i = threadIdx.x; i < HID_D / 4; i += 256) {
    float4 v = xr4[i];
    float4 g = w4[i];
    u16x4 o = { f2bf(v.x * rs * g.x), f2bf(v.y * rs * g.y),
                f2bf(v.z * rs * g.z), f2bf(v.w * rs * g.w) };
    ob[i] = o;
  }
}

// ---------------- fp32 -> bf16 (x4) ----------------
__global__ __launch_bounds__(256) void f2bf4_kernel(const float* __restrict__ in,
                                                    unsigned short* __restrict__ out, int n4) {
  int i = blockIdx.x * 256 + threadIdx.x;
  if (i >= n4) return;
  float4 v = ((const float4*)in)[i];
  u16x4 o = { f2bf(v.x), f2bf(v.y), f2bf(v.z), f2bf(v.w) };
  ((u16x4*)out)[i] = o;
}

// ============ deep-pipelined 256x256 GEMM: C = A[M,K] * B[N,K]^T + bias (+resid) ============
// BK=32, 4 LDS buffers (depth-3 prefetch, counted vmcnt(8)), 8 waves (2Mx4N),
// T2 source/read XOR swizzle, T5 setprio, T1 XCD swizzle. M%256==0, K%32==0.
// NCHECK guards the N edge (B-row clamp + C-col guard).
template <bool NCHECK, bool RESID>
__global__ __launch_bounds__(512, 2) void gemm256(const unsigned short* __restrict__ A,
                                                  const unsigned short* __restrict__ B,
                                                  float* __restrict__ C,
                                                  const float* __restrict__ bias,
                                                  const float* __restrict__ resid,
                                                  int M, int N, int K, int nbx) {
  __shared__ unsigned short sA[4 * 256 * 32];   // 64 KiB
  __shared__ unsigned short sB[4 * 256 * 32];   // 64 KiB

  const int tid = threadIdx.x;
  const int lane = tid & 63, wid = tid >> 6;
  const int wr = wid >> 2, wc = wid & 3;        // 2 x 4 waves
  const int lq = lane & 15, ro = lane >> 4;

  // T1: bijective XCD swizzle (gridDim.x % 8 == 0)
  const int nwg = gridDim.x;
  const int cpx = nwg >> 3;
  const int swz = (blockIdx.x & 7) * cpx + (blockIdx.x >> 3);
  const int bx = swz % nbx, by = swz / nbx;
  const int m0 = by * 256, n0 = bx * 256;

  const int nt = K >> 5;   // K / 32  (>= 4 for both GEMMs here)

  // staging: per thread 4 x gload_lds per tile (2 A rounds + 2 B rounds).
  // LDS linear dest (wave-uniform base + lane*16); source col pre-swizzled:
  // row = rr*128 + tid/4, phys slot = tid&3, logical slot = phys ^ (row&3).
  const int st_row = tid >> 2;                       // 0..127 within half
  const int st_col = (((tid & 3) ^ (st_row & 3)) << 3);
  const size_t aRow0 = (size_t)(m0 + st_row) * K + st_col;
  const size_t aRow1 = (size_t)(m0 + 128 + st_row) * K + st_col;
  int bn0 = n0 + st_row, bn1 = n0 + 128 + st_row;
  if (NCHECK) { bn0 = min(bn0, N - 1); bn1 = min(bn1, N - 1); }
  const size_t bRow0 = (size_t)bn0 * K + st_col;
  const size_t bRow1 = (size_t)bn1 * K + st_col;
  const int ldsOff = wid * 512;                      // ushort units, per-wave base

#define STAGE(kt)                                                        \
  {                                                                      \
    const int _b = (kt) & 3;                                             \
    const int _k0 = (kt) << 5;                                           \
    unsigned short* _ba = sA + _b * (256 * 32);                          \
    unsigned short* _bb = sB + _b * (256 * 32);                          \
    gload_lds16(A + aRow0 + _k0, _ba + ldsOff);                          \
    gload_lds16(B + bRow0 + _k0, _bb + ldsOff);                          \
    gload_lds16(A + aRow1 + _k0, _ba + 4096 + ldsOff);                   \
    gload_lds16(B + bRow1 + _k0, _bb + 4096 + ldsOff);                   \
  }

  STAGE(0); STAGE(1); STAGE(2);

  f32x4 acc[8][4] = {};
  const int slot = ((ro ^ (lq & 3)) << 3);   // swizzled 16B slot (element offset)

  for (int t = 0; t < nt; ++t) {
    // tile t must be resident; tiles t+1, t+2 may stay in flight (4 loads each)
    if (t + 2 < nt)      asm volatile("s_waitcnt vmcnt(8)" ::: "memory");
    else if (t + 1 < nt) asm volatile("s_waitcnt vmcnt(4)" ::: "memory");
    else                 asm volatile("s_waitcnt vmcnt(0)" ::: "memory");
    __builtin_amdgcn_s_barrier();
    __builtin_amdgcn_sched_barrier(0);

    if (t + 3 < nt) STAGE(t + 3);   // overwrites buf[(t-1)&3]: safe after barrier

    const unsigned short* pA = sA + (t & 3) * (256 * 32);
    const unsigned short* pB = sB + (t & 3) * (256 * 32);
    bf16x8 a[8], b[4];
#pragma unroll
    for (int j = 0; j < 4; ++j)
      b[j] = *(const bf16x8*)&pB[(wc * 64 + j * 16 + lq) * 32 + slot];
#pragma unroll
    for (int i = 0; i < 8; ++i)
      a[i] = *(const bf16x8*)&pA[(wr * 128 + i * 16 + lq) * 32 + slot];

    __builtin_amdgcn_s_setprio(1);
#pragma unroll
    for (int i = 0; i < 8; ++i)
#pragma unroll
      for (int j = 0; j < 4; ++j)
        acc[i][j] = __builtin_amdgcn_mfma_f32_16x16x32_bf16(a[i], b[j], acc[i][j], 0, 0, 0);
    __builtin_amdgcn_s_setprio(0);
  }
#undef STAGE

  // epilogue: C[row = m0 + wr*128 + i*16 + ro*4 + r][col = n0 + wc*64 + j*16 + lq]
#pragma unroll
  for (int i = 0; i < 8; ++i) {
    const int gr = m0 + wr * 128 + i * 16 + ro * 4;
#pragma unroll
    for (int j = 0; j < 4; ++j) {
      const int gc = n0 + wc * 64 + j * 16 + lq;
      if (!NCHECK || gc < N) {
        const float bv = bias[gc];
#pragma unroll
        for (int r = 0; r < 4; ++r) {
          size_t off = (size_t)(gr + r) * N + gc;
          float v = acc[i][j][r] + bv;
          if (RESID) v += resid[off];
          C[off] = v;
        }
      }
    }
  }
}

// ---------------- YaRN RoPE (q & k) -> bf16 ----------------
__global__ __launch_bounds__(256) void rope_kernel(const float* __restrict__ qkv,
                                                   const int* __restrict__ positions,
                                                   unsigned short* __restrict__ qb,
                                                   unsigned short* __restrict__ kb) {
  int idx = blockIdx.x * 256 + threadIdx.x;
  const int total = T_SEQ * (NH + NKV) * 32;
  if (idx >= total) return;
  int d = idx & 31;
  int head = (idx >> 5) % (NH + NKV);
  int t = idx / ((NH + NKV) * 32);
  float pw = (float)d * (1.0f / 32.0f);
  float extrap = expf(-pw * 11.9183905733f);  // THETA^-pw
  float interp = extrap * (1.0f / 32.0f);
  float ramp = fminf(fmaxf(((float)d - 8.0f) * 0.1f, 0.0f), 1.0f);
  float invf = interp * ramp + extrap * (1.0f - ramp);
  float fr = (float)positions[t] * invf;
  float s, c;
  sincosf(fr, &s, &c);
  c *= MSCALE;
  s *= MSCALE;
  if (head < NH) {
    const float* b = qkv + (size_t)t * QKV_N + head * HD + d;
    float x1 = b[0], x2 = b[32];
    unsigned short* ob = qb + (size_t)t * ATT_N + head * HD + d;
    ob[0] = f2bf(x1 * c - x2 * s);
    ob[32] = f2bf(x2 * c + x1 * s);
  } else {
    int gk = head - NH;
    const float* b = qkv + (size_t)t * QKV_N + NH * HD + gk * HD + d;
    float x1 = b[0], x2 = b[32];
    unsigned short* ob = kb + (size_t)t * (NKV * HD) + gk * HD + d;
    ob[0] = f2bf(x1 * c - x2 * s);
    ob[32] = f2bf(x2 * c + x1 * s);
  }
}

// ---------------- V transpose -> vt[g][d][t] bf16 ----------------
__global__ __launch_bounds__(256) void vtrans_kernel(const float* __restrict__ qkv,
                                                     unsigned short* __restrict__ vt) {
  int idx = blockIdx.x * 256 + threadIdx.x;  // (g*64+d)*2048 + t
  int t = idx & (T_SEQ - 1);
  int d = (idx >> 11) & 63;
  int g = idx >> 17;
  vt[idx] = f2bf(qkv[(size_t)t * QKV_N + (NH + NKV) * HD + g * HD + d]);
}

// ---------------- sliding-window attention with sinks ----------------
__global__ __launch_bounds__(256) void attn_kernel(const unsigned short* __restrict__ qb,
                                                   const unsigned short* __restrict__ kb,
                                                   const unsigned short* __restrict__ vt,
                                                   const float* __restrict__ sinks,
                                                   unsigned short* __restrict__ att) {
  const int lane = threadIdx.x & 63;
  const int wid = threadIdx.x >> 6;
  const int q0 = blockIdx.x * 16;
  const int h = blockIdx.y * 4 + wid;
  const int g = h >> 3;
  const int lq = lane & 15;
  const int ro = lane >> 4;

  bf16x8 bq0, bq1;
  {
    const unsigned short* qp = qb + (size_t)(q0 + lq) * ATT_N + h * HD + ro * 8;
    bq0 = *(const bf16x8*)qp;
    bq1 = *(const bf16x8*)(qp + 32);
  }
  float m_run = sinks[h];
  float l_run = 1.0f;
  f32x4 o0 = {0.f, 0.f, 0.f, 0.f}, o1 = o0, o2 = o0, o3 = o0;
  const int qg = q0 + lq;
  const int jstart = (q0 >= WIN) ? q0 - WIN : 0;

  for (int jt = jstart; jt <= q0; jt += 32) {
    f32x4 st0 = {0.f, 0.f, 0.f, 0.f}, st1 = st0;
    {
      int kr = jt + ((lq >> 2) << 3) + (lq & 3);
      int kr0 = min(kr, T_SEQ - 1);
      int kr1 = min(kr + 4, T_SEQ - 1);
      const unsigned short* kp0 = kb + (size_t)kr0 * (NKV * HD) + g * HD + ro * 8;
      const unsigned short* kp1 = kb + (size_t)kr1 * (NKV * HD) + g * HD + ro * 8;
      bf16x8 ka0a = *(const bf16x8*)kp0;
      bf16x8 ka0b = *(const bf16x8*)(kp0 + 32);
      bf16x8 ka1a = *(const bf16x8*)kp1;
      bf16x8 ka1b = *(const bf16x8*)(kp1 + 32);
      st0 = __builtin_amdgcn_mfma_f32_16x16x32_bf16(ka0a, bq0, st0, 0, 0, 0);
      st0 = __builtin_amdgcn_mfma_f32_16x16x32_bf16(ka0b, bq1, st0, 0, 0, 0);
      st1 = __builtin_amdgcn_mfma_f32_16x16x32_bf16(ka1a, bq0, st1, 0, 0, 0);
      st1 = __builtin_amdgcn_mfma_f32_16x16x32_bf16(ka1b, bq1, st1, 0, 0, 0);
    }
    float p[8];
    float tmax = -3.0e30f;
#pragma unroll
    for (int r = 0; r < 4; ++r) {
      int jg0 = jt + ro * 8 + r;
      int jg1 = jg0 + 4;
      float s0 = (jg0 <= qg && (qg - jg0) < WIN) ? st0[r] * RSCALE : -3.0e30f;
      float s1 = (jg1 <= qg && (qg - jg1) < WIN) ? st1[r] * RSCALE : -3.0e30f;
      p[r] = s0;
      p[r + 4] = s1;
      tmax = fmaxf(tmax, fmaxf(s0, s1));
    }
    tmax = fmaxf(tmax, __shfl_xor(tmax, 16));
    tmax = fmaxf(tmax, __shfl_xor(tmax, 32));
    float m_new = fmaxf(m_run, tmax);
    float rescale = expf(m_run - m_new);   // factor for q-row lq
    float psum = 0.f;
    bf16x8 pa;
#pragma unroll
    for (int jj = 0; jj < 8; ++jj) {
      float pe = expf(p[jj] - m_new);
      psum += pe;
      pa[jj] = (short)f2bf(pe);
    }
    psum += __shfl_xor(psum, 16);
    psum += __shfl_xor(psum, 32);
    l_run = l_run * rescale + psum;
    m_run = m_new;
    f32x4 rs4;
#pragma unroll
    for (int r = 0; r < 4; ++r) rs4[r] = __shfl(rescale, ro * 4 + r);
    o0 *= rs4; o1 *= rs4; o2 *= rs4; o3 *= rs4;
    int tb = jt + ro * 8;
    if (tb > T_SEQ - 8) tb = T_SEQ - 8;
    const unsigned short* vp = vt + (size_t)(g * HD + lq) * T_SEQ + tb;
    bf16x8 v0 = *(const bf16x8*)vp;
    bf16x8 v1 = *(const bf16x8*)(vp + 16 * T_SEQ);
    bf16x8 v2 = *(const bf16x8*)(vp + 32 * T_SEQ);
    bf16x8 v3 = *(const bf16x8*)(vp + 48 * T_SEQ);
    o0 = __builtin_amdgcn_mfma_f32_16x16x32_bf16(pa, v0, o0, 0, 0, 0);
    o1 = __builtin_amdgcn_mfma_f32_16x16x32_bf16(pa, v1, o1, 0, 0, 0);
    o2 = __builtin_amdgcn_mfma_f32_16x16x32_bf16(pa, v2, o2, 0, 0, 0);
    o3 = __builtin_amdgcn_mfma_f32_16x16x32_bf16(pa, v3, o3, 0, 0, 0);
  }

#pragma unroll
  for (int r = 0; r < 4; ++r) {
    float lr = __shfl(l_run, ro * 4 + r);
    float inv = 1.0f / lr;
    int qrow = q0 + ro * 4 + r;
    unsigned short* op = att + (size_t)qrow * ATT_N + h * HD + lq;
    op[0] = f2bf(o0[r] * inv);
    op[16] = f2bf(o1[r] * inv);
    op[32] = f2bf(o2[r] * inv);
    op[48] = f2bf(o3[r] * inv);
  }
}

extern "C" void kernel_launch(void* const* d_in, const int* in_sizes, int n_in,
                              void* d_out, int out_size, void* d_ws, size_t ws_size,
                              hipStream_t stream) {
  const float* x = (const float*)d_in[0];
  const int* pos = (const int*)d_in[1];
  const float* norm_w = (const float*)d_in[2];
  const float* w_qkv = (const float*)d_in[3];
  const float* b_qkv = (const float*)d_in[4];
  const float* w_o = (const float*)d_in[5];
  const float* b_o = (const float*)d_in[6];
  const float* sinks = (const float*)d_in[7];
  float* out = (float*)d_out;

  unsigned short* t_bf = (unsigned short*)d_ws;                    // [2048][2880]
  unsigned short* wq_bf = t_bf + (size_t)T_SEQ * HID_D;            // [5120][2880]
  unsigned short* wo_bf = wq_bf + (size_t)QKV_N * HID_D;           // [2880][4096]
  float* qkv = (float*)(wo_bf + (size_t)HID_D * ATT_N);            // [2048][5120] fp32
  unsigned short* qb = (unsigned short*)(qkv + (size_t)T_SEQ * QKV_N);  // [2048][4096]
  unsigned short* kb = qb + (size_t)T_SEQ * ATT_N;                 // [2048][512]
  unsigned short* vt = kb + (size_t)T_SEQ * NKV * HD;              // [8][64][2048]
  unsigned short* att = vt + (size_t)NKV * HD * T_SEQ;             // [2048][4096]

  rmsnorm_kernel<<<T_SEQ, 256, 0, stream>>>(x, norm_w, t_bf);
  f2bf4_kernel<<<(QKV_N * HID_D / 4 + 255) / 256, 256, 0, stream>>>(w_qkv, wq_bf, QKV_N * HID_D / 4);
  f2bf4_kernel<<<(HID_D * ATT_N / 4 + 255) / 256, 256, 0, stream>>>(w_o, wo_bf, HID_D * ATT_N / 4);
  // QKV GEMM: M=2048, N=5120, K=2880 -> grid 8 x 20 = 160 blocks
  gemm256<false, false><<<160, 512, 0, stream>>>(
      t_bf, wq_bf, qkv, b_qkv, nullptr, T_SEQ, QKV_N, HID_D, QKV_N / 256);
  rope_kernel<<<(T_SEQ * (NH + NKV) * 32 + 255) / 256, 256, 0, stream>>>(qkv, pos, qb, kb);
  vtrans_kernel<<<(NKV * HD * T_SEQ) / 256, 256, 0, stream>>>(qkv, vt);
  attn_kernel<<<dim3(T_SEQ / 16, NH / 4), 256, 0, stream>>>(qb, kb, vt, sinks, att);
  // out proj: M=2048, N=2880 (edge), K=4096 -> grid 8 x 12 = 96 blocks
  gemm256<true, true><<<96, 512, 0, stream>>>(
      att, wo_bf, out, b_o, x, T_SEQ, HID_D, ATT_N, 12);
}

// Round 4
// 285.829 us; speedup vs baseline: 1.3395x; 1.3395x over previous
//
#include <hip/hip_runtime.h>
#include <hip/hip_bf16.h>
#include <stdint.h>

typedef __attribute__((ext_vector_type(8))) short bf16x8;
typedef __attribute__((ext_vector_type(4))) float f32x4;
typedef __attribute__((ext_vector_type(4))) unsigned short u16x4;

#define T_SEQ 2048
#define HID_D 2880
#define KPAD 2944              // 2880 padded to 46*64 (even K-tile count)
#define NH 64
#define NKV 8
#define HD 64
#define QKV_N 5120
#define ATT_N 4096
#define WIN 128
#define RSCALE 0.125f
#define MSCALE 1.3465735903f

__device__ __forceinline__ unsigned short f2bf(float f) {
  union { float f; unsigned u; } v; v.f = f;
  unsigned r = v.u + 0x7fffu + ((v.u >> 16) & 1u);
  return (unsigned short)(r >> 16);
}

__device__ __forceinline__ void gload_lds16(const void* g, void* l) {
  __builtin_amdgcn_global_load_lds((const __attribute__((address_space(1))) char*)g,
                                   (__attribute__((address_space(3))) char*)l, 16, 0, 0);
}

// ---------------- RMSNorm -> bf16 (K-padded output) ----------------
__global__ __launch_bounds__(256) void rmsnorm_kernel(const float* __restrict__ x,
                                                      const float* __restrict__ w,
                                                      unsigned short* __restrict__ t_bf) {
  int row = blockIdx.x;
  const float4* xr4 = (const float4*)(x + (size_t)row * HID_D);
  const float4* w4 = (const float4*)w;
  float ss = 0.f;
  for (int i = threadIdx.x; i < 720; i += 256) {
    float4 v = xr4[i];
    ss += v.x * v.x + v.y * v.y + v.z * v.z + v.w * v.w;
  }
  __shared__ float red[256];
  red[threadIdx.x] = ss;
  __syncthreads();
  for (int s = 128; s > 0; s >>= 1) {
    if (threadIdx.x < s) red[threadIdx.x] += red[threadIdx.x + s];
    __syncthreads();
  }
  float rs = rsqrtf(red[0] / (float)HID_D + 1e-5f);
  u16x4* ob = (u16x4*)(t_bf + (size_t)row * KPAD);
  for (int i = threadIdx.x; i < 736; i += 256) {
    u16x4 o = {0, 0, 0, 0};
    if (i < 720) {
      float4 v = xr4[i];
      float4 g = w4[i];
      o = { f2bf(v.x * rs * g.x), f2bf(v.y * rs * g.y),
            f2bf(v.z * rs * g.z), f2bf(v.w * rs * g.w) };
    }
    ob[i] = o;
  }
}

// ---------------- fp32 -> bf16, optional K padding ----------------
__global__ __launch_bounds__(256) void f2bf_pad_kernel(const float* __restrict__ in,
                                                       unsigned short* __restrict__ out,
                                                       int rows, int in4, int out4) {
  int i = blockIdx.x * 256 + threadIdx.x;
  if (i >= rows * out4) return;
  int c4 = i % out4, row = i / out4;
  u16x4 o = {0, 0, 0, 0};
  if (c4 < in4) {
    float4 v = ((const float4*)(in + (size_t)row * in4 * 4))[c4];
    o = { f2bf(v.x), f2bf(v.y), f2bf(v.z), f2bf(v.w) };
  }
  ((u16x4*)out)[(size_t)row * out4 + c4] = o;
}

// ============ m201-style 8-phase 256x256 GEMM ============
// C[M,N] = A[M,ld] * B[N,ld]^T (+bias). BK=64, 2 K-tiles/iter, 8 waves (2Mx4N),
// per-wave output 128x64. LDS 128KiB (2 buf x 2 half x 128x64 x A,B).
// Swizzle: granule col ^= (row&3)  (pre-swizzled global source + swizzled read).
// Counted vmcnt(4) at phases 4/8 only. Optional split-K (kslice via grid).
template <bool NCHECK, bool PARTIAL>
__global__ __launch_bounds__(512, 2) void gemm256p(const unsigned short* __restrict__ A,
                                                   const unsigned short* __restrict__ B,
                                                   float* __restrict__ C,
                                                   const float* __restrict__ bias,
                                                   int M, int N, int ld, int nt,
                                                   int nbx, int nbxy, int nstore) {
  __shared__ unsigned short sA[2 * 2 * 128 * 64];   // 64 KiB
  __shared__ unsigned short sB[2 * 2 * 128 * 64];   // 64 KiB

  const int tid = threadIdx.x;
  const int lane = tid & 63, wid = tid >> 6;
  const int wr = wid >> 2, wc = wid & 3;            // 2M x 4N waves
  const int lq = lane & 15, ro = lane >> 4;

  // T1 bijective XCD swizzle (gridDim.x % 8 == 0)
  const int cpx = gridDim.x >> 3;
  const int swz = (blockIdx.x & 7) * cpx + (blockIdx.x >> 3);
  const int kslice = swz / nbxy;
  const int rem = swz - kslice * nbxy;
  const int bx = rem % nbx, by = rem / nbx;
  const int m0 = by * 256, n0 = bx * 256;

  const unsigned short* Ab = A + (size_t)kslice * nt * 64;
  const unsigned short* Bb = B + (size_t)kslice * nt * 64;
  float* Cb = C + (size_t)kslice * M * nstore;

  // ---- staging addresses (2 gloads per half-tile; rounds r=0,1 -> rows R0, R0+64)
  const int R0 = tid >> 3;                               // 0..63
  const int g0 = (((tid & 7) ^ (R0 & 3)) << 3);          // swizzled source granule (elems)
  const size_t aOff = (size_t)(m0 + R0) * ld + g0;
  size_t bOff[2][2];
#pragma unroll
  for (int h = 0; h < 2; ++h)
#pragma unroll
    for (int r = 0; r < 2; ++r) {
      int rr = n0 + h * 128 + r * 64 + R0;
      if (NCHECK) rr = min(rr, N - 1);
      bOff[h][r] = (size_t)rr * ld + g0;
    }

  // ---- ds_read swizzled column base: granule (kk*4+ro)^(lq&3) -> elems ck0 + kk*32
  const int ck0 = ((ro ^ (lq & 3)) << 3);

#define STG_A(BUF, H, KT)                                                        \
  { unsigned short* _d = sA + ((BUF) * 2 + (H)) * 8192 + wid * 512;              \
    const unsigned short* _s = Ab + aOff + (size_t)((H) * 128) * ld + (KT) * 64; \
    gload_lds16(_s, _d); gload_lds16(_s + (size_t)64 * ld, _d + 4096); }
#define STG_B(BUF, H, KT)                                                        \
  { unsigned short* _d = sB + ((BUF) * 2 + (H)) * 8192 + wid * 512;              \
    gload_lds16(Bb + bOff[H][0] + (KT) * 64, _d);                                \
    gload_lds16(Bb + bOff[H][1] + (KT) * 64, _d + 4096); }

  bf16x8 aR[8];
  bf16x8 bR0[4], bR1[4];
  f32x4 acc[8][4] = {};

#define LDA(BUF, S)                                                                        \
  { _Pragma("unroll") for (int ii = 0; ii < 4; ++ii) {                                     \
      const int _r = ((BUF) * 2 + wr) * 8192 + ((S) * 64 + ii * 16 + lq) * 64 + ck0;       \
      aR[ii * 2 + 0] = *(const bf16x8*)&sA[_r];                                            \
      aR[ii * 2 + 1] = *(const bf16x8*)&sA[_r + 32]; } }
#define LDB(BUF, NHF, DST)                                                                 \
  { _Pragma("unroll") for (int jj = 0; jj < 2; ++jj) {                                     \
      const int _r = ((BUF) * 2 + (wc >> 1)) * 8192 +                                      \
                     ((wc & 1) * 64 + ((NHF) * 2 + jj) * 16 + lq) * 64 + ck0;              \
      DST[jj * 2 + 0] = *(const bf16x8*)&sB[_r];                                           \
      DST[jj * 2 + 1] = *(const bf16x8*)&sB[_r + 32]; } }
#define MFMA16(S, NHF, BREG)                                                               \
  { _Pragma("unroll") for (int ii = 0; ii < 4; ++ii)                                       \
    _Pragma("unroll") for (int jj = 0; jj < 2; ++jj)                                       \
    _Pragma("unroll") for (int kk = 0; kk < 2; ++kk)                                       \
      acc[(S) * 4 + ii][(NHF) * 2 + jj] = __builtin_amdgcn_mfma_f32_16x16x32_bf16(         \
          aR[ii * 2 + kk], BREG[jj * 2 + kk], acc[(S) * 4 + ii][(NHF) * 2 + jj], 0, 0, 0); }
#define PH_MID()                                         \
  __builtin_amdgcn_s_barrier();                          \
  asm volatile("s_waitcnt lgkmcnt(0)" ::: "memory");     \
  __builtin_amdgcn_sched_barrier(0);                     \
  __builtin_amdgcn_s_setprio(1)
#define PH_END()                                         \
  __builtin_amdgcn_s_setprio(0);                         \
  __builtin_amdgcn_s_barrier()

  // prologue: tile0 (A0,A1,B0,B1) + tile1 (B0,B1); wait first 4 stage-ops
  STG_A(0, 0, 0); STG_A(0, 1, 0); STG_B(0, 0, 0); STG_B(0, 1, 0);
  STG_B(1, 0, 1); STG_B(1, 1, 1);
  asm volatile("s_waitcnt vmcnt(4)" ::: "memory");
  __builtin_amdgcn_s_barrier();

  const int niter = nt >> 1;
  for (int it = 0; it < niter; ++it) {
    const int t = it * 2;
    const bool more = (it + 1 < niter);
    // P1: reads tile t (buf0) a-sub0 + b-nh0; stage A0(t+1)->buf1
    LDA(0, 0); LDB(0, 0, bR0); STG_A(1, 0, t + 1);
    PH_MID(); MFMA16(0, 0, bR0); PH_END();
    // P2: b-nh1; stage A1(t+1)
    LDB(0, 1, bR1); STG_A(1, 1, t + 1);
    PH_MID(); MFMA16(0, 1, bR1); PH_END();
    // P3: a-sub1; stage B0(t+2)->buf0 (B regions of buf0 free after P2)
    LDA(0, 1); if (more) STG_B(0, 0, t + 2);
    PH_MID(); MFMA16(1, 1, bR1); PH_END();
    // P4: no reads; stage B1(t+2); WAIT1 covers tile t+1
    if (more) STG_B(0, 1, t + 2);
    PH_MID(); MFMA16(1, 0, bR0);
    __builtin_amdgcn_s_setprio(0);
    if (more) asm volatile("s_waitcnt vmcnt(4)" ::: "memory");
    else      asm volatile("s_waitcnt vmcnt(0)" ::: "memory");
    __builtin_amdgcn_s_barrier();
    // P5: tile t+1 (buf1) a-sub0 + b-nh0; stage A0(t+2) (A regions of buf0 free after P3)
    LDA(1, 0); LDB(1, 0, bR0); if (more) STG_A(0, 0, t + 2);
    PH_MID(); MFMA16(0, 0, bR0); PH_END();
    // P6: b-nh1; stage A1(t+2)
    LDB(1, 1, bR1); if (more) STG_A(0, 1, t + 2);
    PH_MID(); MFMA16(0, 1, bR1); PH_END();
    // P7: a-sub1; stage B0(t+3)->buf1 (B of buf1 free after P6)
    LDA(1, 1); if (more) STG_B(1, 0, t + 3);
    PH_MID(); MFMA16(1, 1, bR1); PH_END();
    // P8: stage B1(t+3); WAIT2 covers tile t+2
    if (more) STG_B(1, 1, t + 3);
    PH_MID(); MFMA16(1, 0, bR0);
    __builtin_amdgcn_s_setprio(0);
    if (more) asm volatile("s_waitcnt vmcnt(4)" ::: "memory");
    else      asm volatile("s_waitcnt vmcnt(0)" ::: "memory");
    __builtin_amdgcn_s_barrier();
  }
#undef STG_A
#undef STG_B
#undef LDA
#undef LDB
#undef MFMA16
#undef PH_MID
#undef PH_END

  // epilogue
#pragma unroll
  for (int fi = 0; fi < 8; ++fi) {
    const int gr = m0 + wr * 128 + fi * 16 + ro * 4;
#pragma unroll
    for (int j = 0; j < 4; ++j) {
      const int gc = n0 + wc * 64 + j * 16 + lq;
      if (!NCHECK || gc < N) {
        const float bv = PARTIAL ? 0.0f : bias[gc];
#pragma unroll
        for (int r = 0; r < 4; ++r)
          Cb[(size_t)(gr + r) * nstore + gc] = acc[fi][j][r] + bv;
      }
    }
  }
}

// ---------------- split-K reduce + bias + residual ----------------
__global__ __launch_bounds__(256) void reduce_out_kernel(const float* __restrict__ part,
                                                         const float* __restrict__ bias,
                                                         const float* __restrict__ x,
                                                         float* __restrict__ out) {
  int i = blockIdx.x * 256 + threadIdx.x;
  if (i >= T_SEQ * 720) return;
  int c4 = i % 720, row = i / 720;
  size_t off = (size_t)row * HID_D + c4 * 4;
  float4 a = *(const float4*)(part + off);
  float4 b = *(const float4*)(part + (size_t)T_SEQ * HID_D + off);
  float4 bv = ((const float4*)bias)[c4];
  float4 xv = *(const float4*)(x + off);
  float4 o = { a.x + b.x + bv.x + xv.x, a.y + b.y + bv.y + xv.y,
               a.z + b.z + bv.z + xv.z, a.w + b.w + bv.w + xv.w };
  *(float4*)(out + off) = o;
}

// ---------------- YaRN RoPE (q & k) -> bf16 ----------------
__global__ __launch_bounds__(256) void rope_kernel(const float* __restrict__ qkv,
                                                   const int* __restrict__ positions,
                                                   unsigned short* __restrict__ qb,
                                                   unsigned short* __restrict__ kb) {
  int idx = blockIdx.x * 256 + threadIdx.x;
  const int total = T_SEQ * (NH + NKV) * 32;
  if (idx >= total) return;
  int d = idx & 31;
  int head = (idx >> 5) % (NH + NKV);
  int t = idx / ((NH + NKV) * 32);
  float pw = (float)d * (1.0f / 32.0f);
  float extrap = expf(-pw * 11.9183905733f);
  float interp = extrap * (1.0f / 32.0f);
  float ramp = fminf(fmaxf(((float)d - 8.0f) * 0.1f, 0.0f), 1.0f);
  float invf = interp * ramp + extrap * (1.0f - ramp);
  float fr = (float)positions[t] * invf;
  float s, c;
  sincosf(fr, &s, &c);
  c *= MSCALE;
  s *= MSCALE;
  if (head < NH) {
    const float* b = qkv + (size_t)t * QKV_N + head * HD + d;
    float x1 = b[0], x2 = b[32];
    unsigned short* ob = qb + (size_t)t * ATT_N + head * HD + d;
    ob[0] = f2bf(x1 * c - x2 * s);
    ob[32] = f2bf(x2 * c + x1 * s);
  } else {
    int gk = head - NH;
    const float* b = qkv + (size_t)t * QKV_N + NH * HD + gk * HD + d;
    float x1 = b[0], x2 = b[32];
    unsigned short* ob = kb + (size_t)t * (NKV * HD) + gk * HD + d;
    ob[0] = f2bf(x1 * c - x2 * s);
    ob[32] = f2bf(x2 * c + x1 * s);
  }
}

// ---------------- V transpose -> vt[g][d][t] bf16 ----------------
__global__ __launch_bounds__(256) void vtrans_kernel(const float* __restrict__ qkv,
                                                     unsigned short* __restrict__ vt) {
  int idx = blockIdx.x * 256 + threadIdx.x;
  int t = idx & (T_SEQ - 1);
  int d = (idx >> 11) & 63;
  int g = idx >> 17;
  vt[idx] = f2bf(qkv[(size_t)t * QKV_N + (NH + NKV) * HD + g * HD + d]);
}

// ---------------- sliding-window attention with sinks ----------------
__global__ __launch_bounds__(256) void attn_kernel(const unsigned short* __restrict__ qb,
                                                   const unsigned short* __restrict__ kb,
                                                   const unsigned short* __restrict__ vt,
                                                   const float* __restrict__ sinks,
                                                   unsigned short* __restrict__ att) {
  const int lane = threadIdx.x & 63;
  const int wid = threadIdx.x >> 6;
  const int q0 = blockIdx.x * 16;
  const int h = blockIdx.y * 4 + wid;
  const int g = h >> 3;
  const int lq = lane & 15;
  const int ro = lane >> 4;

  bf16x8 bq0, bq1;
  {
    const unsigned short* qp = qb + (size_t)(q0 + lq) * ATT_N + h * HD + ro * 8;
    bq0 = *(const bf16x8*)qp;
    bq1 = *(const bf16x8*)(qp + 32);
  }
  float m_run = sinks[h];
  float l_run = 1.0f;
  f32x4 o0 = {0.f, 0.f, 0.f, 0.f}, o1 = o0, o2 = o0, o3 = o0;
  const int qg = q0 + lq;
  const int jstart = (q0 >= WIN) ? q0 - WIN : 0;

  for (int jt = jstart; jt <= q0; jt += 32) {
    f32x4 st0 = {0.f, 0.f, 0.f, 0.f}, st1 = st0;
    {
      int kr = jt + ((lq >> 2) << 3) + (lq & 3);
      int kr0 = min(kr, T_SEQ - 1);
      int kr1 = min(kr + 4, T_SEQ - 1);
      const unsigned short* kp0 = kb + (size_t)kr0 * (NKV * HD) + g * HD + ro * 8;
      const unsigned short* kp1 = kb + (size_t)kr1 * (NKV * HD) + g * HD + ro * 8;
      bf16x8 ka0a = *(const bf16x8*)kp0;
      bf16x8 ka0b = *(const bf16x8*)(kp0 + 32);
      bf16x8 ka1a = *(const bf16x8*)kp1;
      bf16x8 ka1b = *(const bf16x8*)(kp1 + 32);
      st0 = __builtin_amdgcn_mfma_f32_16x16x32_bf16(ka0a, bq0, st0, 0, 0, 0);
      st0 = __builtin_amdgcn_mfma_f32_16x16x32_bf16(ka0b, bq1, st0, 0, 0, 0);
      st1 = __builtin_amdgcn_mfma_f32_16x16x32_bf16(ka1a, bq0, st1, 0, 0, 0);
      st1 = __builtin_amdgcn_mfma_f32_16x16x32_bf16(ka1b, bq1, st1, 0, 0, 0);
    }
    float p[8];
    float tmax = -3.0e30f;
#pragma unroll
    for (int r = 0; r < 4; ++r) {
      int jg0 = jt + ro * 8 + r;
      int jg1 = jg0 + 4;
      float s0 = (jg0 <= qg && (qg - jg0) < WIN) ? st0[r] * RSCALE : -3.0e30f;
      float s1 = (jg1 <= qg && (qg - jg1) < WIN) ? st1[r] * RSCALE : -3.0e30f;
      p[r] = s0;
      p[r + 4] = s1;
      tmax = fmaxf(tmax, fmaxf(s0, s1));
    }
    tmax = fmaxf(tmax, __shfl_xor(tmax, 16));
    tmax = fmaxf(tmax, __shfl_xor(tmax, 32));
    float m_new = fmaxf(m_run, tmax);
    float rescale = expf(m_run - m_new);
    float psum = 0.f;
    bf16x8 pa;
#pragma unroll
    for (int jj = 0; jj < 8; ++jj) {
      float pe = expf(p[jj] - m_new);
      psum += pe;
      pa[jj] = (short)f2bf(pe);
    }
    psum += __shfl_xor(psum, 16);
    psum += __shfl_xor(psum, 32);
    l_run = l_run * rescale + psum;
    m_run = m_new;
    f32x4 rs4;
#pragma unroll
    for (int r = 0; r < 4; ++r) rs4[r] = __shfl(rescale, ro * 4 + r);
    o0 *= rs4; o1 *= rs4; o2 *= rs4; o3 *= rs4;
    int tb = jt + ro * 8;
    if (tb > T_SEQ - 8) tb = T_SEQ - 8;
    const unsigned short* vp = vt + (size_t)(g * HD + lq) * T_SEQ + tb;
    bf16x8 v0 = *(const bf16x8*)vp;
    bf16x8 v1 = *(const bf16x8*)(vp + 16 * T_SEQ);
    bf16x8 v2 = *(const bf16x8*)(vp + 32 * T_SEQ);
    bf16x8 v3 = *(const bf16x8*)(vp + 48 * T_SEQ);
    o0 = __builtin_amdgcn_mfma_f32_16x16x32_bf16(pa, v0, o0, 0, 0, 0);
    o1 = __builtin_amdgcn_mfma_f32_16x16x32_bf16(pa, v1, o1, 0, 0, 0);
    o2 = __builtin_amdgcn_mfma_f32_16x16x32_bf16(pa, v2, o2, 0, 0, 0);
    o3 = __builtin_amdgcn_mfma_f32_16x16x32_bf16(pa, v3, o3, 0, 0, 0);
  }

#pragma unroll
  for (int r = 0; r < 4; ++r) {
    float lr = __shfl(l_run, ro * 4 + r);
    float inv = 1.0f / lr;
    int qrow = q0 + ro * 4 + r;
    unsigned short* op = att + (size_t)qrow * ATT_N + h * HD + lq;
    op[0] = f2bf(o0[r] * inv);
    op[16] = f2bf(o1[r] * inv);
    op[32] = f2bf(o2[r] * inv);
    op[48] = f2bf(o3[r] * inv);
  }
}

extern "C" void kernel_launch(void* const* d_in, const int* in_sizes, int n_in,
                              void* d_out, int out_size, void* d_ws, size_t ws_size,
                              hipStream_t stream) {
  const float* x = (const float*)d_in[0];
  const int* pos = (const int*)d_in[1];
  const float* norm_w = (const float*)d_in[2];
  const float* w_qkv = (const float*)d_in[3];
  const float* b_qkv = (const float*)d_in[4];
  const float* w_o = (const float*)d_in[5];
  const float* b_o = (const float*)d_in[6];
  const float* sinks = (const float*)d_in[7];
  float* out = (float*)d_out;

  unsigned short* t_bf = (unsigned short*)d_ws;                    // [2048][2944]
  unsigned short* wq_bf = t_bf + (size_t)T_SEQ * KPAD;             // [5120][2944]
  unsigned short* wo_bf = wq_bf + (size_t)QKV_N * KPAD;            // [2880][4096]
  float* qkv = (float*)(wo_bf + (size_t)HID_D * ATT_N);            // [2048][5120] fp32
  unsigned short* qb = (unsigned short*)(qkv + (size_t)T_SEQ * QKV_N);  // [2048][4096]
  unsigned short* kb = qb + (size_t)T_SEQ * ATT_N;                 // [2048][512]
  unsigned short* vt = kb + (size_t)T_SEQ * NKV * HD;              // [8][64][2048]
  unsigned short* att = vt + (size_t)NKV * HD * T_SEQ;             // [2048][4096]
  // split-K partials [2][2048][2880] fp32 reuse the dead qkv/qb region
  float* part = qkv;

  rmsnorm_kernel<<<T_SEQ, 256, 0, stream>>>(x, norm_w, t_bf);
  f2bf_pad_kernel<<<(QKV_N * 736 + 255) / 256, 256, 0, stream>>>(w_qkv, wq_bf, QKV_N, 720, 736);
  f2bf_pad_kernel<<<(HID_D * 1024 + 255) / 256, 256, 0, stream>>>(w_o, wo_bf, HID_D, 1024, 1024);
  // QKV GEMM: M=2048 N=5120 K=2944(padded) -> 8x20 = 160 blocks
  gemm256p<false, false><<<160, 512, 0, stream>>>(
      t_bf, wq_bf, qkv, b_qkv, T_SEQ, QKV_N, KPAD, 46, 20, 160, QKV_N);
  rope_kernel<<<(T_SEQ * (NH + NKV) * 32 + 255) / 256, 256, 0, stream>>>(qkv, pos, qb, kb);
  vtrans_kernel<<<(NKV * HD * T_SEQ) / 256, 256, 0, stream>>>(qkv, vt);
  attn_kernel<<<dim3(T_SEQ / 16, NH / 4), 256, 0, stream>>>(qb, kb, vt, sinks, att);
  // out proj, split-K=2: M=2048 N=2880 K=4096 -> 2 x (8x12) = 192 blocks
  gemm256p<true, true><<<192, 512, 0, stream>>>(
      att, wo_bf, part, b_o, T_SEQ, HID_D, ATT_N, 32, 12, 96, HID_D);
  reduce_out_kernel<<<(T_SEQ * 720 + 255) / 256, 256, 0, stream>>>(part, b_o, x, out);
}

// Round 5
// 265.065 us; speedup vs baseline: 1.4444x; 1.0783x over previous
//
#include <hip/hip_runtime.h>
#include <hip/hip_bf16.h>
#include <stdint.h>

typedef __attribute__((ext_vector_type(8))) short bf16x8;
typedef __attribute__((ext_vector_type(4))) float f32x4;
typedef __attribute__((ext_vector_type(4))) unsigned short u16x4;

#define T_SEQ 2048
#define HID_D 2880
#define KPAD 2944              // 2880 padded to 46*64 (even K-tile count)
#define NH 64
#define NKV 8
#define HD 64
#define QKV_N 5120
#define ATT_N 4096
#define WIN 128
#define RSCALE 0.125f
#define MSCALE 1.3465735903f

__device__ __forceinline__ unsigned short f2bf(float f) {
  union { float f; unsigned u; } v; v.f = f;
  unsigned r = v.u + 0x7fffu + ((v.u >> 16) & 1u);
  return (unsigned short)(r >> 16);
}

__device__ __forceinline__ void gload_lds16(const void* g, void* l) {
  __builtin_amdgcn_global_load_lds((const __attribute__((address_space(1))) char*)g,
                                   (__attribute__((address_space(3))) char*)l, 16, 0, 0);
}

// ---------------- RMSNorm -> bf16 (K-padded output) ----------------
__global__ __launch_bounds__(256) void rmsnorm_kernel(const float* __restrict__ x,
                                                      const float* __restrict__ w,
                                                      unsigned short* __restrict__ t_bf) {
  int row = blockIdx.x;
  const float4* xr4 = (const float4*)(x + (size_t)row * HID_D);
  const float4* w4 = (const float4*)w;
  float ss = 0.f;
  for (int i = threadIdx.x; i < 720; i += 256) {
    float4 v = xr4[i];
    ss += v.x * v.x + v.y * v.y + v.z * v.z + v.w * v.w;
  }
  __shared__ float red[256];
  red[threadIdx.x] = ss;
  __syncthreads();
  for (int s = 128; s > 0; s >>= 1) {
    if (threadIdx.x < s) red[threadIdx.x] += red[threadIdx.x + s];
    __syncthreads();
  }
  float rs = rsqrtf(red[0] / (float)HID_D + 1e-5f);
  u16x4* ob = (u16x4*)(t_bf + (size_t)row * KPAD);
  for (int i = threadIdx.x; i < 736; i += 256) {
    u16x4 o = {0, 0, 0, 0};
    if (i < 720) {
      float4 v = xr4[i];
      float4 g = w4[i];
      o = { f2bf(v.x * rs * g.x), f2bf(v.y * rs * g.y),
            f2bf(v.z * rs * g.z), f2bf(v.w * rs * g.w) };
    }
    ob[i] = o;
  }
}

// ---------------- fp32 -> bf16, optional K padding ----------------
__global__ __launch_bounds__(256) void f2bf_pad_kernel(const float* __restrict__ in,
                                                       unsigned short* __restrict__ out,
                                                       int rows, int in4, int out4) {
  int i = blockIdx.x * 256 + threadIdx.x;
  if (i >= rows * out4) return;
  int c4 = i % out4, row = i / out4;
  u16x4 o = {0, 0, 0, 0};
  if (c4 < in4) {
    float4 v = ((const float4*)(in + (size_t)row * in4 * 4))[c4];
    o = { f2bf(v.x), f2bf(v.y), f2bf(v.z), f2bf(v.w) };
  }
  ((u16x4*)out)[(size_t)row * out4 + c4] = o;
}

// ============ m201-style 8-phase 256x256 GEMM ============
// C[M,N] = A[M,ld] * B[N,ld]^T (+bias). BK=64, 2 K-tiles/iter, 8 waves (2Mx4N),
// per-wave output 128x64. LDS 128KiB (2 buf x 2 half x 128x64 x A,B).
// T2 swizzle (FULL 3-bit): LDS physical granule p of row r holds global
// granule p^(r&7); stage source pre-swizzled, ds_read applies p=G^(r&7).
// Every 8-consecutive-lane b128 group covers all 8 granules -> conflict-free.
// Counted vmcnt(4) at phases 4/8 only. Optional split-K (kslice via grid).
template <bool NCHECK, bool PARTIAL>
__global__ __launch_bounds__(512, 2) void gemm256p(const unsigned short* __restrict__ A,
                                                   const unsigned short* __restrict__ B,
                                                   float* __restrict__ C,
                                                   const float* __restrict__ bias,
                                                   int M, int N, int ld, int nt,
                                                   int nbx, int nbxy, int nstore) {
  __shared__ unsigned short sA[2 * 2 * 128 * 64];   // 64 KiB
  __shared__ unsigned short sB[2 * 2 * 128 * 64];   // 64 KiB

  const int tid = threadIdx.x;
  const int lane = tid & 63, wid = tid >> 6;
  const int wr = wid >> 2, wc = wid & 3;            // 2M x 4N waves
  const int lq = lane & 15, ro = lane >> 4;

  // T1 bijective XCD swizzle (gridDim.x % 8 == 0)
  const int cpx = gridDim.x >> 3;
  const int swz = (blockIdx.x & 7) * cpx + (blockIdx.x >> 3);
  const int kslice = swz / nbxy;
  const int rem = swz - kslice * nbxy;
  const int bx = rem % nbx, by = rem / nbx;
  const int m0 = by * 256, n0 = bx * 256;

  const unsigned short* Ab = A + (size_t)kslice * nt * 64;
  const unsigned short* Bb = B + (size_t)kslice * nt * 64;
  float* Cb = C + (size_t)kslice * M * nstore;

  // ---- staging addresses (2 gloads per half-tile; rows R0, R0+64)
  const int R0 = tid >> 3;                               // 0..63
  const int g0 = (((tid & 7) ^ (R0 & 7)) << 3);          // pre-swizzled source granule
  const size_t aOff = (size_t)(m0 + R0) * ld + g0;
  size_t bOff[2][2];
#pragma unroll
  for (int h = 0; h < 2; ++h)
#pragma unroll
    for (int r = 0; r < 2; ++r) {
      int rr = n0 + h * 128 + r * 64 + R0;
      if (NCHECK) rr = min(rr, N - 1);
      bOff[h][r] = (size_t)rr * ld + g0;
    }

  // ---- ds_read swizzled columns: physical granule (kk*4+ro)^(lq&7), elems
  const int ck0 = ((ro ^ (lq & 7)) << 3);
  const int ck1 = (((4 + ro) ^ (lq & 7)) << 3);

#define STG_A(BUF, H, KT)                                                        \
  { unsigned short* _d = sA + ((BUF) * 2 + (H)) * 8192 + wid * 512;              \
    const unsigned short* _s = Ab + aOff + (size_t)((H) * 128) * ld + (KT) * 64; \
    gload_lds16(_s, _d); gload_lds16(_s + (size_t)64 * ld, _d + 4096); }
#define STG_B(BUF, H, KT)                                                        \
  { unsigned short* _d = sB + ((BUF) * 2 + (H)) * 8192 + wid * 512;              \
    gload_lds16(Bb + bOff[H][0] + (KT) * 64, _d);                                \
    gload_lds16(Bb + bOff[H][1] + (KT) * 64, _d + 4096); }

  bf16x8 aR[8];
  bf16x8 bR0[4], bR1[4];
  f32x4 acc[8][4] = {};

#define LDA(BUF, S)                                                                        \
  { _Pragma("unroll") for (int ii = 0; ii < 4; ++ii) {                                     \
      const int _r = ((BUF) * 2 + wr) * 8192 + ((S) * 64 + ii * 16 + lq) * 64;             \
      aR[ii * 2 + 0] = *(const bf16x8*)&sA[_r + ck0];                                      \
      aR[ii * 2 + 1] = *(const bf16x8*)&sA[_r + ck1]; } }
#define LDB(BUF, NHF, DST)                                                                 \
  { _Pragma("unroll") for (int jj = 0; jj < 2; ++jj) {                                     \
      const int _r = ((BUF) * 2 + (wc >> 1)) * 8192 +                                      \
                     ((wc & 1) * 64 + ((NHF) * 2 + jj) * 16 + lq) * 64;                    \
      DST[jj * 2 + 0] = *(const bf16x8*)&sB[_r + ck0];                                     \
      DST[jj * 2 + 1] = *(const bf16x8*)&sB[_r + ck1]; } }
#define MFMA16(S, NHF, BREG)                                                               \
  { _Pragma("unroll") for (int ii = 0; ii < 4; ++ii)                                       \
    _Pragma("unroll") for (int jj = 0; jj < 2; ++jj)                                       \
    _Pragma("unroll") for (int kk = 0; kk < 2; ++kk)                                       \
      acc[(S) * 4 + ii][(NHF) * 2 + jj] = __builtin_amdgcn_mfma_f32_16x16x32_bf16(         \
          aR[ii * 2 + kk], BREG[jj * 2 + kk], acc[(S) * 4 + ii][(NHF) * 2 + jj], 0, 0, 0); }
#define PH_MID()                                         \
  __builtin_amdgcn_s_barrier();                          \
  asm volatile("s_waitcnt lgkmcnt(0)" ::: "memory");     \
  __builtin_amdgcn_sched_barrier(0);                     \
  __builtin_amdgcn_s_setprio(1)
#define PH_END()                                         \
  __builtin_amdgcn_s_setprio(0);                         \
  __builtin_amdgcn_s_barrier()

  // prologue: tile0 (A0,A1,B0,B1) + tile1 (B0,B1); wait first 4 stage-ops
  STG_A(0, 0, 0); STG_A(0, 1, 0); STG_B(0, 0, 0); STG_B(0, 1, 0);
  STG_B(1, 0, 1); STG_B(1, 1, 1);
  asm volatile("s_waitcnt vmcnt(4)" ::: "memory");
  __builtin_amdgcn_s_barrier();

  const int niter = nt >> 1;
  for (int it = 0; it < niter; ++it) {
    const int t = it * 2;
    const bool more = (it + 1 < niter);
    // P1: reads tile t (buf0) a-sub0 + b-nh0; stage A0(t+1)->buf1
    LDA(0, 0); LDB(0, 0, bR0); STG_A(1, 0, t + 1);
    PH_MID(); MFMA16(0, 0, bR0); PH_END();
    // P2: b-nh1; stage A1(t+1)
    LDB(0, 1, bR1); STG_A(1, 1, t + 1);
    PH_MID(); MFMA16(0, 1, bR1); PH_END();
    // P3: a-sub1; stage B0(t+2)->buf0 (B regions of buf0 free after P2)
    LDA(0, 1); if (more) STG_B(0, 0, t + 2);
    PH_MID(); MFMA16(1, 1, bR1); PH_END();
    // P4: no reads; stage B1(t+2); WAIT1 covers tile t+1
    if (more) STG_B(0, 1, t + 2);
    PH_MID(); MFMA16(1, 0, bR0);
    __builtin_amdgcn_s_setprio(0);
    if (more) asm volatile("s_waitcnt vmcnt(4)" ::: "memory");
    else      asm volatile("s_waitcnt vmcnt(0)" ::: "memory");
    __builtin_amdgcn_s_barrier();
    // P5: tile t+1 (buf1) a-sub0 + b-nh0; stage A0(t+2)
    LDA(1, 0); LDB(1, 0, bR0); if (more) STG_A(0, 0, t + 2);
    PH_MID(); MFMA16(0, 0, bR0); PH_END();
    // P6: b-nh1; stage A1(t+2)
    LDB(1, 1, bR1); if (more) STG_A(0, 1, t + 2);
    PH_MID(); MFMA16(0, 1, bR1); PH_END();
    // P7: a-sub1; stage B0(t+3)->buf1 (B of buf1 free after P6)
    LDA(1, 1); if (more) STG_B(1, 0, t + 3);
    PH_MID(); MFMA16(1, 1, bR1); PH_END();
    // P8: stage B1(t+3); WAIT2 covers tile t+2
    if (more) STG_B(1, 1, t + 3);
    PH_MID(); MFMA16(1, 0, bR0);
    __builtin_amdgcn_s_setprio(0);
    if (more) asm volatile("s_waitcnt vmcnt(4)" ::: "memory");
    else      asm volatile("s_waitcnt vmcnt(0)" ::: "memory");
    __builtin_amdgcn_s_barrier();
  }
#undef STG_A
#undef STG_B
#undef LDA
#undef LDB
#undef MFMA16
#undef PH_MID
#undef PH_END

  // epilogue
#pragma unroll
  for (int fi = 0; fi < 8; ++fi) {
    const int gr = m0 + wr * 128 + fi * 16 + ro * 4;
#pragma unroll
    for (int j = 0; j < 4; ++j) {
      const int gc = n0 + wc * 64 + j * 16 + lq;
      if (!NCHECK || gc < N) {
        const float bv = PARTIAL ? 0.0f : bias[gc];
#pragma unroll
        for (int r = 0; r < 4; ++r)
          Cb[(size_t)(gr + r) * nstore + gc] = acc[fi][j][r] + bv;
      }
    }
  }
}

// ---------------- split-K reduce + bias + residual ----------------
__global__ __launch_bounds__(256) void reduce_out_kernel(const float* __restrict__ part,
                                                         const float* __restrict__ bias,
                                                         const float* __restrict__ x,
                                                         float* __restrict__ out) {
  int i = blockIdx.x * 256 + threadIdx.x;
  if (i >= T_SEQ * 720) return;
  int c4 = i % 720, row = i / 720;
  size_t off = (size_t)row * HID_D + c4 * 4;
  float4 a = *(const float4*)(part + off);
  float4 b = *(const float4*)(part + (size_t)T_SEQ * HID_D + off);
  float4 bv = ((const float4*)bias)[c4];
  float4 xv = *(const float4*)(x + off);
  float4 o = { a.x + b.x + bv.x + xv.x, a.y + b.y + bv.y + xv.y,
               a.z + b.z + bv.z + xv.z, a.w + b.w + bv.w + xv.w };
  *(float4*)(out + off) = o;
}

// ---------------- YaRN RoPE (q & k) -> bf16 ----------------
__global__ __launch_bounds__(256) void rope_kernel(const float* __restrict__ qkv,
                                                   const int* __restrict__ positions,
                                                   unsigned short* __restrict__ qb,
                                                   unsigned short* __restrict__ kb) {
  int idx = blockIdx.x * 256 + threadIdx.x;
  const int total = T_SEQ * (NH + NKV) * 32;
  if (idx >= total) return;
  int d = idx & 31;
  int head = (idx >> 5) % (NH + NKV);
  int t = idx / ((NH + NKV) * 32);
  float pw = (float)d * (1.0f / 32.0f);
  float extrap = expf(-pw * 11.9183905733f);
  float interp = extrap * (1.0f / 32.0f);
  float ramp = fminf(fmaxf(((float)d - 8.0f) * 0.1f, 0.0f), 1.0f);
  float invf = interp * ramp + extrap * (1.0f - ramp);
  float fr = (float)positions[t] * invf;
  float s, c;
  sincosf(fr, &s, &c);
  c *= MSCALE;
  s *= MSCALE;
  if (head < NH) {
    const float* b = qkv + (size_t)t * QKV_N + head * HD + d;
    float x1 = b[0], x2 = b[32];
    unsigned short* ob = qb + (size_t)t * ATT_N + head * HD + d;
    ob[0] = f2bf(x1 * c - x2 * s);
    ob[32] = f2bf(x2 * c + x1 * s);
  } else {
    int gk = head - NH;
    const float* b = qkv + (size_t)t * QKV_N + NH * HD + gk * HD + d;
    float x1 = b[0], x2 = b[32];
    unsigned short* ob = kb + (size_t)t * (NKV * HD) + gk * HD + d;
    ob[0] = f2bf(x1 * c - x2 * s);
    ob[32] = f2bf(x2 * c + x1 * s);
  }
}

// ---------------- V transpose -> vt[g][d][t] bf16 ----------------
__global__ __launch_bounds__(256) void vtrans_kernel(const float* __restrict__ qkv,
                                                     unsigned short* __restrict__ vt) {
  int idx = blockIdx.x * 256 + threadIdx.x;
  int t = idx & (T_SEQ - 1);
  int d = (idx >> 11) & 63;
  int g = idx >> 17;
  vt[idx] = f2bf(qkv[(size_t)t * QKV_N + (NH + NKV) * HD + g * HD + d]);
}

// ---------------- sliding-window attention with sinks ----------------
__global__ __launch_bounds__(256) void attn_kernel(const unsigned short* __restrict__ qb,
                                                   const unsigned short* __restrict__ kb,
                                                   const unsigned short* __restrict__ vt,
                                                   const float* __restrict__ sinks,
                                                   unsigned short* __restrict__ att) {
  const int lane = threadIdx.x & 63;
  const int wid = threadIdx.x >> 6;
  const int q0 = blockIdx.x * 16;
  const int h = blockIdx.y * 4 + wid;
  const int g = h >> 3;
  const int lq = lane & 15;
  const int ro = lane >> 4;

  bf16x8 bq0, bq1;
  {
    const unsigned short* qp = qb + (size_t)(q0 + lq) * ATT_N + h * HD + ro * 8;
    bq0 = *(const bf16x8*)qp;
    bq1 = *(const bf16x8*)(qp + 32);
  }
  float m_run = sinks[h];
  float l_run = 1.0f;
  f32x4 o0 = {0.f, 0.f, 0.f, 0.f}, o1 = o0, o2 = o0, o3 = o0;
  const int qg = q0 + lq;
  const int jstart = (q0 >= WIN) ? q0 - WIN : 0;

  for (int jt = jstart; jt <= q0; jt += 32) {
    f32x4 st0 = {0.f, 0.f, 0.f, 0.f}, st1 = st0;
    {
      int kr = jt + ((lq >> 2) << 3) + (lq & 3);
      int kr0 = min(kr, T_SEQ - 1);
      int kr1 = min(kr + 4, T_SEQ - 1);
      const unsigned short* kp0 = kb + (size_t)kr0 * (NKV * HD) + g * HD + ro * 8;
      const unsigned short* kp1 = kb + (size_t)kr1 * (NKV * HD) + g * HD + ro * 8;
      bf16x8 ka0a = *(const bf16x8*)kp0;
      bf16x8 ka0b = *(const bf16x8*)(kp0 + 32);
      bf16x8 ka1a = *(const bf16x8*)kp1;
      bf16x8 ka1b = *(const bf16x8*)(kp1 + 32);
      st0 = __builtin_amdgcn_mfma_f32_16x16x32_bf16(ka0a, bq0, st0, 0, 0, 0);
      st0 = __builtin_amdgcn_mfma_f32_16x16x32_bf16(ka0b, bq1, st0, 0, 0, 0);
      st1 = __builtin_amdgcn_mfma_f32_16x16x32_bf16(ka1a, bq0, st1, 0, 0, 0);
      st1 = __builtin_amdgcn_mfma_f32_16x16x32_bf16(ka1b, bq1, st1, 0, 0, 0);
    }
    float p[8];
    float tmax = -3.0e30f;
#pragma unroll
    for (int r = 0; r < 4; ++r) {
      int jg0 = jt + ro * 8 + r;
      int jg1 = jg0 + 4;
      float s0 = (jg0 <= qg && (qg - jg0) < WIN) ? st0[r] * RSCALE : -3.0e30f;
      float s1 = (jg1 <= qg && (qg - jg1) < WIN) ? st1[r] * RSCALE : -3.0e30f;
      p[r] = s0;
      p[r + 4] = s1;
      tmax = fmaxf(tmax, fmaxf(s0, s1));
    }
    tmax = fmaxf(tmax, __shfl_xor(tmax, 16));
    tmax = fmaxf(tmax, __shfl_xor(tmax, 32));
    float m_new = fmaxf(m_run, tmax);
    float rescale = expf(m_run - m_new);
    float psum = 0.f;
    bf16x8 pa;
#pragma unroll
    for (int jj = 0; jj < 8; ++jj) {
      float pe = expf(p[jj] - m_new);
      psum += pe;
      pa[jj] = (short)f2bf(pe);
    }
    psum += __shfl_xor(psum, 16);
    psum += __shfl_xor(psum, 32);
    l_run = l_run * rescale + psum;
    m_run = m_new;
    f32x4 rs4;
#pragma unroll
    for (int r = 0; r < 4; ++r) rs4[r] = __shfl(rescale, ro * 4 + r);
    o0 *= rs4; o1 *= rs4; o2 *= rs4; o3 *= rs4;
    int tb = jt + ro * 8;
    if (tb > T_SEQ - 8) tb = T_SEQ - 8;
    const unsigned short* vp = vt + (size_t)(g * HD + lq) * T_SEQ + tb;
    bf16x8 v0 = *(const bf16x8*)vp;
    bf16x8 v1 = *(const bf16x8*)(vp + 16 * T_SEQ);
    bf16x8 v2 = *(const bf16x8*)(vp + 32 * T_SEQ);
    bf16x8 v3 = *(const bf16x8*)(vp + 48 * T_SEQ);
    o0 = __builtin_amdgcn_mfma_f32_16x16x32_bf16(pa, v0, o0, 0, 0, 0);
    o1 = __builtin_amdgcn_mfma_f32_16x16x32_bf16(pa, v1, o1, 0, 0, 0);
    o2 = __builtin_amdgcn_mfma_f32_16x16x32_bf16(pa, v2, o2, 0, 0, 0);
    o3 = __builtin_amdgcn_mfma_f32_16x16x32_bf16(pa, v3, o3, 0, 0, 0);
  }

#pragma unroll
  for (int r = 0; r < 4; ++r) {
    float lr = __shfl(l_run, ro * 4 + r);
    float inv = 1.0f / lr;
    int qrow = q0 + ro * 4 + r;
    unsigned short* op = att + (size_t)qrow * ATT_N + h * HD + lq;
    op[0] = f2bf(o0[r] * inv);
    op[16] = f2bf(o1[r] * inv);
    op[32] = f2bf(o2[r] * inv);
    op[48] = f2bf(o3[r] * inv);
  }
}

extern "C" void kernel_launch(void* const* d_in, const int* in_sizes, int n_in,
                              void* d_out, int out_size, void* d_ws, size_t ws_size,
                              hipStream_t stream) {
  const float* x = (const float*)d_in[0];
  const int* pos = (const int*)d_in[1];
  const float* norm_w = (const float*)d_in[2];
  const float* w_qkv = (const float*)d_in[3];
  const float* b_qkv = (const float*)d_in[4];
  const float* w_o = (const float*)d_in[5];
  const float* b_o = (const float*)d_in[6];
  const float* sinks = (const float*)d_in[7];
  float* out = (float*)d_out;

  unsigned short* t_bf = (unsigned short*)d_ws;                    // [2048][2944]
  unsigned short* wq_bf = t_bf + (size_t)T_SEQ * KPAD;             // [5120][2944]
  unsigned short* wo_bf = wq_bf + (size_t)QKV_N * KPAD;            // [2880][4096]
  float* qkv = (float*)(wo_bf + (size_t)HID_D * ATT_N);            // [2048][5120] fp32
  unsigned short* qb = (unsigned short*)(qkv + (size_t)T_SEQ * QKV_N);  // [2048][4096]
  unsigned short* kb = qb + (size_t)T_SEQ * ATT_N;                 // [2048][512]
  unsigned short* vt = kb + (size_t)T_SEQ * NKV * HD;              // [8][64][2048]
  unsigned short* att = vt + (size_t)NKV * HD * T_SEQ;             // [2048][4096]
  // split-K partials [2][2048][2880] fp32 reuse the dead qkv/qb region
  float* part = qkv;

  rmsnorm_kernel<<<T_SEQ, 256, 0, stream>>>(x, norm_w, t_bf);
  f2bf_pad_kernel<<<(QKV_N * 736 + 255) / 256, 256, 0, stream>>>(w_qkv, wq_bf, QKV_N, 720, 736);
  f2bf_pad_kernel<<<(HID_D * 1024 + 255) / 256, 256, 0, stream>>>(w_o, wo_bf, HID_D, 1024, 1024);
  // QKV GEMM: M=2048 N=5120 K=2944(padded) -> 8x20 = 160 blocks
  gemm256p<false, false><<<160, 512, 0, stream>>>(
      t_bf, wq_bf, qkv, b_qkv, T_SEQ, QKV_N, KPAD, 46, 20, 160, QKV_N);
  rope_kernel<<<(T_SEQ * (NH + NKV) * 32 + 255) / 256, 256, 0, stream>>>(qkv, pos, qb, kb);
  vtrans_kernel<<<(NKV * HD * T_SEQ) / 256, 256, 0, stream>>>(qkv, vt);
  attn_kernel<<<dim3(T_SEQ / 16, NH / 4), 256, 0, stream>>>(qb, kb, vt, sinks, att);
  // out proj, split-K=2: M=2048 N=2880 K=4096 -> 2 x (8x12) = 192 blocks
  gemm256p<true, true><<<192, 512, 0, stream>>>(
      att, wo_bf, part, b_o, T_SEQ, HID_D, ATT_N, 32, 12, 96, HID_D);
  reduce_out_kernel<<<(T_SEQ * 720 + 255) / 256, 256, 0, stream>>>(part, b_o, x, out);
}

// Round 6
// 252.669 us; speedup vs baseline: 1.5153x; 1.0491x over previous
//
#include <hip/hip_runtime.h>
#include <hip/hip_bf16.h>
#include <stdint.h>

typedef __attribute__((ext_vector_type(8))) short bf16x8;
typedef __attribute__((ext_vector_type(4))) float f32x4;
typedef __attribute__((ext_vector_type(4))) unsigned short u16x4;

#define T_SEQ 2048
#define HID_D 2880
#define KPAD 2944              // 2880 padded to 46*64
#define NH 64
#define NKV 8
#define HD 64
#define QKV_N 5120
#define ATT_N 4096
#define WIN 128
#define RSCALE 0.125f
#define MSCALE 1.3465735903f
#define ROPE_TOT (T_SEQ * (NH + NKV) * 32)   // 4718592
#define VT_TOT (NKV * HD * T_SEQ)            // 1048576

__device__ __forceinline__ unsigned short f2bf(float f) {
  union { float f; unsigned u; } v; v.f = f;
  unsigned r = v.u + 0x7fffu + ((v.u >> 16) & 1u);
  return (unsigned short)(r >> 16);
}
__device__ __forceinline__ float bf2f(unsigned short u) {
  union { unsigned u; float f; } v; v.u = ((unsigned)u) << 16;
  return v.f;
}

__device__ __forceinline__ void gload_lds16(const void* g, void* l) {
  __builtin_amdgcn_global_load_lds((const __attribute__((address_space(1))) char*)g,
                                   (__attribute__((address_space(3))) char*)l, 16, 0, 0);
}

// ---------------- fused RMSNorm (blocks 0..2047) + w_qkv->bf16 pad (blocks 2048..3071) ----------------
__global__ __launch_bounds__(256) void pre_kernel(const float* __restrict__ x,
                                                  const float* __restrict__ w,
                                                  unsigned short* __restrict__ t_bf,
                                                  const float* __restrict__ wq_src,
                                                  unsigned short* __restrict__ wq_dst) {
  __shared__ float red[256];
  if (blockIdx.x < 2048) {
    int row = blockIdx.x;
    const float4* xr4 = (const float4*)(x + (size_t)row * HID_D);
    const float4* w4 = (const float4*)w;
    float ss = 0.f;
    for (int i = threadIdx.x; i < 720; i += 256) {
      float4 v = xr4[i];
      ss += v.x * v.x + v.y * v.y + v.z * v.z + v.w * v.w;
    }
    red[threadIdx.x] = ss;
    __syncthreads();
    for (int s = 128; s > 0; s >>= 1) {
      if (threadIdx.x < s) red[threadIdx.x] += red[threadIdx.x + s];
      __syncthreads();
    }
    float rs = rsqrtf(red[0] / (float)HID_D + 1e-5f);
    u16x4* ob = (u16x4*)(t_bf + (size_t)row * KPAD);
    for (int i = threadIdx.x; i < 736; i += 256) {
      u16x4 o = {0, 0, 0, 0};
      if (i < 720) {
        float4 v = xr4[i];
        float4 g = w4[i];
        o = { f2bf(v.x * rs * g.x), f2bf(v.y * rs * g.y),
              f2bf(v.z * rs * g.z), f2bf(v.w * rs * g.w) };
      }
      ob[i] = o;
    }
  } else {
    const int total = QKV_N * 736;
    for (int i = (blockIdx.x - 2048) * 256 + threadIdx.x; i < total; i += 1024 * 256) {
      int c4 = i % 736, row = i / 736;
      u16x4 o = {0, 0, 0, 0};
      if (c4 < 720) {
        float4 v = ((const float4*)wq_src)[(size_t)row * 720 + c4];
        o = { f2bf(v.x), f2bf(v.y), f2bf(v.z), f2bf(v.w) };
      }
      ((u16x4*)wq_dst)[i] = o;
    }
  }
}

// ============ 8-phase 256x256 GEMM body (shared by QKV and out-proj) ============
// MODE 2: single-K, bf16 output + bias.  MODE 1: split-K fp32; kslice0 -> out(+bias+resid),
// kslice1 -> part (raw). Full 3-bit T2 swizzle (source-preswizzled + swizzled ds_read).
template <bool NCHECK, int MODE>
__device__ __forceinline__ void gemm_body(const unsigned short* __restrict__ A,
                                          const unsigned short* __restrict__ B,
                                          void* __restrict__ C0,
                                          float* __restrict__ Cpart,
                                          const float* __restrict__ bias,
                                          const float* __restrict__ resid,
                                          int M, int N, int ld, int nt,
                                          int nbx, int nbxy, int nstore, int swz,
                                          unsigned short* sA, unsigned short* sB) {
  const int tid = threadIdx.x;
  const int lane = tid & 63, wid = tid >> 6;
  const int wr = wid >> 2, wc = wid & 3;
  const int lq = lane & 15, ro = lane >> 4;

  const int kslice = swz / nbxy;
  const int rem = swz - kslice * nbxy;
  const int bx = rem % nbx, by = rem / nbx;
  const int m0 = by * 256, n0 = bx * 256;

  const unsigned short* Ab = A + (size_t)kslice * nt * 64;
  const unsigned short* Bb = B + (size_t)kslice * nt * 64;

  const int R0 = tid >> 3;
  const int g0 = (((tid & 7) ^ (R0 & 7)) << 3);
  const size_t aOff = (size_t)(m0 + R0) * ld + g0;
  size_t bOff[2][2];
#pragma unroll
  for (int h = 0; h < 2; ++h)
#pragma unroll
    for (int r = 0; r < 2; ++r) {
      int rr = n0 + h * 128 + r * 64 + R0;
      if (NCHECK) rr = min(rr, N - 1);
      bOff[h][r] = (size_t)rr * ld + g0;
    }

  const int ck0 = ((ro ^ (lq & 7)) << 3);
  const int ck1 = (((4 + ro) ^ (lq & 7)) << 3);

#define STG_A(BUF, H, KT)                                                        \
  { unsigned short* _d = sA + ((BUF) * 2 + (H)) * 8192 + wid * 512;              \
    const unsigned short* _s = Ab + aOff + (size_t)((H) * 128) * ld + (KT) * 64; \
    gload_lds16(_s, _d); gload_lds16(_s + (size_t)64 * ld, _d + 4096); }
#define STG_B(BUF, H, KT)                                                        \
  { unsigned short* _d = sB + ((BUF) * 2 + (H)) * 8192 + wid * 512;              \
    gload_lds16(Bb + bOff[H][0] + (KT) * 64, _d);                                \
    gload_lds16(Bb + bOff[H][1] + (KT) * 64, _d + 4096); }

  bf16x8 aR[8];
  bf16x8 bR0[4], bR1[4];
  f32x4 acc[8][4] = {};

#define LDA(BUF, S)                                                                        \
  { _Pragma("unroll") for (int ii = 0; ii < 4; ++ii) {                                     \
      const int _r = ((BUF) * 2 + wr) * 8192 + ((S) * 64 + ii * 16 + lq) * 64;             \
      aR[ii * 2 + 0] = *(const bf16x8*)&sA[_r + ck0];                                      \
      aR[ii * 2 + 1] = *(const bf16x8*)&sA[_r + ck1]; } }
#define LDB(BUF, NHF, DST)                                                                 \
  { _Pragma("unroll") for (int jj = 0; jj < 2; ++jj) {                                     \
      const int _r = ((BUF) * 2 + (wc >> 1)) * 8192 +                                      \
                     ((wc & 1) * 64 + ((NHF) * 2 + jj) * 16 + lq) * 64;                    \
      DST[jj * 2 + 0] = *(const bf16x8*)&sB[_r + ck0];                                     \
      DST[jj * 2 + 1] = *(const bf16x8*)&sB[_r + ck1]; } }
#define MFMA16(S, NHF, BREG)                                                               \
  { _Pragma("unroll") for (int ii = 0; ii < 4; ++ii)                                       \
    _Pragma("unroll") for (int jj = 0; jj < 2; ++jj)                                       \
    _Pragma("unroll") for (int kk = 0; kk < 2; ++kk)                                       \
      acc[(S) * 4 + ii][(NHF) * 2 + jj] = __builtin_amdgcn_mfma_f32_16x16x32_bf16(         \
          aR[ii * 2 + kk], BREG[jj * 2 + kk], acc[(S) * 4 + ii][(NHF) * 2 + jj], 0, 0, 0); }
#define PH_MID()                                         \
  __builtin_amdgcn_s_barrier();                          \
  asm volatile("s_waitcnt lgkmcnt(0)" ::: "memory");     \
  __builtin_amdgcn_sched_barrier(0);                     \
  __builtin_amdgcn_s_setprio(1)
#define PH_END()                                         \
  __builtin_amdgcn_s_setprio(0);                         \
  __builtin_amdgcn_s_barrier()

  STG_A(0, 0, 0); STG_A(0, 1, 0); STG_B(0, 0, 0); STG_B(0, 1, 0);
  STG_B(1, 0, 1); STG_B(1, 1, 1);
  asm volatile("s_waitcnt vmcnt(4)" ::: "memory");
  __builtin_amdgcn_s_barrier();

  const int niter = nt >> 1;
  for (int it = 0; it < niter; ++it) {
    const int t = it * 2;
    const bool more = (it + 1 < niter);
    LDA(0, 0); LDB(0, 0, bR0); STG_A(1, 0, t + 1);
    PH_MID(); MFMA16(0, 0, bR0); PH_END();
    LDB(0, 1, bR1); STG_A(1, 1, t + 1);
    PH_MID(); MFMA16(0, 1, bR1); PH_END();
    LDA(0, 1); if (more) STG_B(0, 0, t + 2);
    PH_MID(); MFMA16(1, 1, bR1); PH_END();
    if (more) STG_B(0, 1, t + 2);
    PH_MID(); MFMA16(1, 0, bR0);
    __builtin_amdgcn_s_setprio(0);
    if (more) asm volatile("s_waitcnt vmcnt(4)" ::: "memory");
    else      asm volatile("s_waitcnt vmcnt(0)" ::: "memory");
    __builtin_amdgcn_s_barrier();
    LDA(1, 0); LDB(1, 0, bR0); if (more) STG_A(0, 0, t + 2);
    PH_MID(); MFMA16(0, 0, bR0); PH_END();
    LDB(1, 1, bR1); if (more) STG_A(0, 1, t + 2);
    PH_MID(); MFMA16(0, 1, bR1); PH_END();
    LDA(1, 1); if (more) STG_B(1, 0, t + 3);
    PH_MID(); MFMA16(1, 1, bR1); PH_END();
    if (more) STG_B(1, 1, t + 3);
    PH_MID(); MFMA16(1, 0, bR0);
    __builtin_amdgcn_s_setprio(0);
    if (more) asm volatile("s_waitcnt vmcnt(4)" ::: "memory");
    else      asm volatile("s_waitcnt vmcnt(0)" ::: "memory");
    __builtin_amdgcn_s_barrier();
  }
#undef STG_A
#undef STG_B
#undef LDA
#undef LDB
#undef MFMA16
#undef PH_MID
#undef PH_END

#pragma unroll
  for (int fi = 0; fi < 8; ++fi) {
    const int gr = m0 + wr * 128 + fi * 16 + ro * 4;
#pragma unroll
    for (int j = 0; j < 4; ++j) {
      const int gc = n0 + wc * 64 + j * 16 + lq;
      if (!NCHECK || gc < N) {
        if (MODE == 2) {
          const float bv = bias[gc];
          unsigned short* Cs = (unsigned short*)C0;
#pragma unroll
          for (int r = 0; r < 4; ++r)
            Cs[(size_t)(gr + r) * nstore + gc] = f2bf(acc[fi][j][r] + bv);
        } else {
          if (kslice == 0) {
            float* Cf = (float*)C0;
            const float bv = bias[gc];
#pragma unroll
            for (int r = 0; r < 4; ++r) {
              size_t off = (size_t)(gr + r) * nstore + gc;
              Cf[off] = acc[fi][j][r] + bv + resid[off];
            }
          } else {
#pragma unroll
            for (int r = 0; r < 4; ++r)
              Cpart[(size_t)(gr + r) * nstore + gc] = acc[fi][j][r];
          }
        }
      }
    }
  }
}

// ---------------- QKV GEMM (160 blocks) fused with w_o->bf16 conversion (96 blocks) ----------------
__global__ __launch_bounds__(512, 2) void qkv_fused_kernel(const unsigned short* __restrict__ A,
                                                           const unsigned short* __restrict__ B,
                                                           unsigned short* __restrict__ C,
                                                           const float* __restrict__ bias,
                                                           const float* __restrict__ wo_src,
                                                           unsigned short* __restrict__ wo_dst) {
  __shared__ unsigned short sA[2 * 2 * 128 * 64];
  __shared__ unsigned short sB[2 * 2 * 128 * 64];
  const int c = blockIdx.x & 7, q = blockIdx.x >> 3;
  if (q < 20) {
    // each XCD owns M-row c (by == c): 20 N-tiles share one A-panel in L2
    gemm_body<false, 2>(A, B, C, nullptr, bias, nullptr,
                        T_SEQ, QKV_N, KPAD, 46, 20, 160, QKV_N, c * 20 + q, sA, sB);
  } else {
    const int cid = c * 12 + (q - 20);            // 0..95
    const int total = HID_D * 1024;               // float4 count of w_o
    for (int i = cid * 512 + threadIdx.x; i < total; i += 96 * 512) {
      float4 v = ((const float4*)wo_src)[i];
      u16x4 o = { f2bf(v.x), f2bf(v.y), f2bf(v.z), f2bf(v.w) };
      ((u16x4*)wo_dst)[i] = o;
    }
  }
}

// ---------------- out projection, split-K=2 (192 blocks) ----------------
__global__ __launch_bounds__(512, 2) void outproj_kernel(const unsigned short* __restrict__ att,
                                                         const unsigned short* __restrict__ wo_bf,
                                                         float* __restrict__ out,
                                                         float* __restrict__ part,
                                                         const float* __restrict__ b_o,
                                                         const float* __restrict__ x) {
  __shared__ unsigned short sA[2 * 2 * 128 * 64];
  __shared__ unsigned short sB[2 * 2 * 128 * 64];
  const int swz = (blockIdx.x & 7) * 24 + (blockIdx.x >> 3);
  gemm_body<true, 1>(att, wo_bf, out, part, b_o, x,
                     T_SEQ, HID_D, ATT_N, 32, 12, 96, HID_D, swz, sA, sB);
}

// ---------------- split-K reduce: out += part ----------------
__global__ __launch_bounds__(256) void reduce_add_kernel(float* __restrict__ out,
                                                         const float* __restrict__ part) {
  int i = blockIdx.x * 256 + threadIdx.x;
  if (i >= T_SEQ * 720) return;
  float4 o = ((const float4*)out)[i];
  float4 p = ((const float4*)part)[i];
  o.x += p.x; o.y += p.y; o.z += p.z; o.w += p.w;
  ((float4*)out)[i] = o;
}

// ---------------- fused YaRN RoPE (q,k) + V transpose, reading bf16 qkv ----------------
__global__ __launch_bounds__(256) void ropev_kernel(const unsigned short* __restrict__ qkvb,
                                                    const int* __restrict__ positions,
                                                    unsigned short* __restrict__ qb,
                                                    unsigned short* __restrict__ kb,
                                                    unsigned short* __restrict__ vt) {
  int idx = blockIdx.x * 256 + threadIdx.x;
  if (idx < ROPE_TOT) {
    int d = idx & 31;
    int head = (idx >> 5) % (NH + NKV);
    int t = idx / ((NH + NKV) * 32);
    float pw = (float)d * (1.0f / 32.0f);
    float extrap = expf(-pw * 11.9183905733f);
    float interp = extrap * (1.0f / 32.0f);
    float ramp = fminf(fmaxf(((float)d - 8.0f) * 0.1f, 0.0f), 1.0f);
    float invf = interp * ramp + extrap * (1.0f - ramp);
    float fr = (float)positions[t] * invf;
    float s, c;
    sincosf(fr, &s, &c);
    c *= MSCALE;
    s *= MSCALE;
    if (head < NH) {
      const unsigned short* b = qkvb + (size_t)t * QKV_N + head * HD + d;
      float x1 = bf2f(b[0]), x2 = bf2f(b[32]);
      unsigned short* ob = qb + (size_t)t * ATT_N + head * HD + d;
      ob[0] = f2bf(x1 * c - x2 * s);
      ob[32] = f2bf(x2 * c + x1 * s);
    } else {
      int gk = head - NH;
      const unsigned short* b = qkvb + (size_t)t * QKV_N + NH * HD + gk * HD + d;
      float x1 = bf2f(b[0]), x2 = bf2f(b[32]);
      unsigned short* ob = kb + (size_t)t * (NKV * HD) + gk * HD + d;
      ob[0] = f2bf(x1 * c - x2 * s);
      ob[32] = f2bf(x2 * c + x1 * s);
    }
  } else {
    int i2 = idx - ROPE_TOT;                      // (g*64+d)*2048 + t
    int t = i2 & (T_SEQ - 1);
    int d = (i2 >> 11) & 63;
    int g = i2 >> 17;
    vt[i2] = qkvb[(size_t)t * QKV_N + (NH + NKV) * HD + g * HD + d];
  }
}

// ---------------- sliding-window attention with sinks ----------------
__global__ __launch_bounds__(256) void attn_kernel(const unsigned short* __restrict__ qb,
                                                   const unsigned short* __restrict__ kb,
                                                   const unsigned short* __restrict__ vt,
                                                   const float* __restrict__ sinks,
                                                   unsigned short* __restrict__ att) {
  const int lane = threadIdx.x & 63;
  const int wid = threadIdx.x >> 6;
  const int q0 = blockIdx.x * 16;
  const int h = blockIdx.y * 4 + wid;
  const int g = h >> 3;
  const int lq = lane & 15;
  const int ro = lane >> 4;

  bf16x8 bq0, bq1;
  {
    const unsigned short* qp = qb + (size_t)(q0 + lq) * ATT_N + h * HD + ro * 8;
    bq0 = *(const bf16x8*)qp;
    bq1 = *(const bf16x8*)(qp + 32);
  }
  float m_run = sinks[h];
  float l_run = 1.0f;
  f32x4 o0 = {0.f, 0.f, 0.f, 0.f}, o1 = o0, o2 = o0, o3 = o0;
  const int qg = q0 + lq;
  const int jstart = (q0 >= WIN) ? q0 - WIN : 0;

  for (int jt = jstart; jt <= q0; jt += 32) {
    f32x4 st0 = {0.f, 0.f, 0.f, 0.f}, st1 = st0;
    {
      int kr = jt + ((lq >> 2) << 3) + (lq & 3);
      int kr0 = min(kr, T_SEQ - 1);
      int kr1 = min(kr + 4, T_SEQ - 1);
      const unsigned short* kp0 = kb + (size_t)kr0 * (NKV * HD) + g * HD + ro * 8;
      const unsigned short* kp1 = kb + (size_t)kr1 * (NKV * HD) + g * HD + ro * 8;
      bf16x8 ka0a = *(const bf16x8*)kp0;
      bf16x8 ka0b = *(const bf16x8*)(kp0 + 32);
      bf16x8 ka1a = *(const bf16x8*)kp1;
      bf16x8 ka1b = *(const bf16x8*)(kp1 + 32);
      st0 = __builtin_amdgcn_mfma_f32_16x16x32_bf16(ka0a, bq0, st0, 0, 0, 0);
      st0 = __builtin_amdgcn_mfma_f32_16x16x32_bf16(ka0b, bq1, st0, 0, 0, 0);
      st1 = __builtin_amdgcn_mfma_f32_16x16x32_bf16(ka1a, bq0, st1, 0, 0, 0);
      st1 = __builtin_amdgcn_mfma_f32_16x16x32_bf16(ka1b, bq1, st1, 0, 0, 0);
    }
    float p[8];
    float tmax = -3.0e30f;
#pragma unroll
    for (int r = 0; r < 4; ++r) {
      int jg0 = jt + ro * 8 + r;
      int jg1 = jg0 + 4;
      float s0 = (jg0 <= qg && (qg - jg0) < WIN) ? st0[r] * RSCALE : -3.0e30f;
      float s1 = (jg1 <= qg && (qg - jg1) < WIN) ? st1[r] * RSCALE : -3.0e30f;
      p[r] = s0;
      p[r + 4] = s1;
      tmax = fmaxf(tmax, fmaxf(s0, s1));
    }
    tmax = fmaxf(tmax, __shfl_xor(tmax, 16));
    tmax = fmaxf(tmax, __shfl_xor(tmax, 32));
    float m_new = fmaxf(m_run, tmax);
    float rescale = expf(m_run - m_new);
    float psum = 0.f;
    bf16x8 pa;
#pragma unroll
    for (int jj = 0; jj < 8; ++jj) {
      float pe = expf(p[jj] - m_new);
      psum += pe;
      pa[jj] = (short)f2bf(pe);
    }
    psum += __shfl_xor(psum, 16);
    psum += __shfl_xor(psum, 32);
    l_run = l_run * rescale + psum;
    m_run = m_new;
    f32x4 rs4;
#pragma unroll
    for (int r = 0; r < 4; ++r) rs4[r] = __shfl(rescale, ro * 4 + r);
    o0 *= rs4; o1 *= rs4; o2 *= rs4; o3 *= rs4;
    int tb = jt + ro * 8;
    if (tb > T_SEQ - 8) tb = T_SEQ - 8;
    const unsigned short* vp = vt + (size_t)(g * HD + lq) * T_SEQ + tb;
    bf16x8 v0 = *(const bf16x8*)vp;
    bf16x8 v1 = *(const bf16x8*)(vp + 16 * T_SEQ);
    bf16x8 v2 = *(const bf16x8*)(vp + 32 * T_SEQ);
    bf16x8 v3 = *(const bf16x8*)(vp + 48 * T_SEQ);
    o0 = __builtin_amdgcn_mfma_f32_16x16x32_bf16(pa, v0, o0, 0, 0, 0);
    o1 = __builtin_amdgcn_mfma_f32_16x16x32_bf16(pa, v1, o1, 0, 0, 0);
    o2 = __builtin_amdgcn_mfma_f32_16x16x32_bf16(pa, v2, o2, 0, 0, 0);
    o3 = __builtin_amdgcn_mfma_f32_16x16x32_bf16(pa, v3, o3, 0, 0, 0);
  }

#pragma unroll
  for (int r = 0; r < 4; ++r) {
    float lr = __shfl(l_run, ro * 4 + r);
    float inv = 1.0f / lr;
    int qrow = q0 + ro * 4 + r;
    unsigned short* op = att + (size_t)qrow * ATT_N + h * HD + lq;
    op[0] = f2bf(o0[r] * inv);
    op[16] = f2bf(o1[r] * inv);
    op[32] = f2bf(o2[r] * inv);
    op[48] = f2bf(o3[r] * inv);
  }
}

extern "C" void kernel_launch(void* const* d_in, const int* in_sizes, int n_in,
                              void* d_out, int out_size, void* d_ws, size_t ws_size,
                              hipStream_t stream) {
  const float* x = (const float*)d_in[0];
  const int* pos = (const int*)d_in[1];
  const float* norm_w = (const float*)d_in[2];
  const float* w_qkv = (const float*)d_in[3];
  const float* b_qkv = (const float*)d_in[4];
  const float* w_o = (const float*)d_in[5];
  const float* b_o = (const float*)d_in[6];
  const float* sinks = (const float*)d_in[7];
  float* out = (float*)d_out;

  unsigned short* t_bf = (unsigned short*)d_ws;                        // [2048][2944]
  unsigned short* wq_bf = t_bf + (size_t)T_SEQ * KPAD;                 // [5120][2944]
  unsigned short* wo_bf = wq_bf + (size_t)QKV_N * KPAD;                // [2880][4096]
  unsigned short* qkv_bf = wo_bf + (size_t)HID_D * ATT_N;              // [2048][5120] bf16
  unsigned short* qb = qkv_bf + (size_t)T_SEQ * QKV_N;                 // [2048][4096]
  unsigned short* kb = qb + (size_t)T_SEQ * ATT_N;                     // [2048][512]
  unsigned short* vt = kb + (size_t)T_SEQ * NKV * HD;                  // [8][64][2048]
  unsigned short* att = vt + (size_t)NKV * HD * T_SEQ;                 // [2048][4096]
  // fp32 split-K partial [2048][2880] reuses dead t_bf/wq_bf region (live only after attn)
  float* part = (float*)d_ws;

  // 1. RMSNorm + w_qkv conversion
  pre_kernel<<<3072, 256, 0, stream>>>(x, norm_w, t_bf, w_qkv, wq_bf);
  // 2. QKV GEMM (160 blocks) + w_o conversion (96 blocks) = full 256-block grid
  qkv_fused_kernel<<<256, 512, 0, stream>>>(t_bf, wq_bf, qkv_bf, b_qkv, w_o, wo_bf);
  // 3. RoPE + V transpose
  ropev_kernel<<<(ROPE_TOT + VT_TOT) / 256, 256, 0, stream>>>(qkv_bf, pos, qb, kb, vt);
  // 4. attention
  attn_kernel<<<dim3(T_SEQ / 16, NH / 4), 256, 0, stream>>>(qb, kb, vt, sinks, att);
  // 5. out projection split-K=2
  outproj_kernel<<<192, 512, 0, stream>>>(att, wo_bf, out, part, b_o, x);
  // 6. out += part
  reduce_add_kernel<<<(T_SEQ * 720 + 255) / 256, 256, 0, stream>>>(out, part);
}